// Round 6
// baseline (165.749 us; speedup 1.0000x reference)
//
#include <hip/hip_runtime.h>

typedef __bf16 bf16x8 __attribute__((ext_vector_type(8)));
typedef float f32x4 __attribute__((ext_vector_type(4)));

// ---------------------------------------------------------------------------
// Repack all three W [H=128][K] fp32 -> bf16 MFMA fragments (used as the "A"
// operand): dst[((ks*8 + hf)*64 + lane)*8 + e] =
//   bf16(W[hf*16 + (lane&15)][ks*32 + (lane>>4)*8 + e])
// ---------------------------------------------------------------------------
__global__ void prep_all_kernel(const float* __restrict__ W0, const float* __restrict__ W1,
                                const float* __restrict__ W2,
                                __bf16* __restrict__ Bf0, __bf16* __restrict__ Bf1,
                                __bf16* __restrict__ Bf2) {
    int t = blockIdx.x * blockDim.x + threadIdx.x;
    const float* W;
    __bf16* dst;
    int K;
    if (t < 1024)      { W = W0; dst = Bf0; K = 64; }
    else if (t < 3072) { W = W1; dst = Bf1; K = 128; t -= 1024; }
    else if (t < 7168) { W = W2; dst = Bf2; K = 256; t -= 3072; }
    else return;
    int lane = t & 63;
    int hf = (t >> 6) & 7;
    int ks = t >> 9;
    int row = hf * 16 + (lane & 15);
    int k0 = ks * 32 + ((lane >> 4) << 3);
    const float* src = W + (size_t)row * K + k0;
    __bf16* d = dst + (size_t)t * 8;
#pragma unroll
    for (int e = 0; e < 8; ++e) d[e] = (__bf16)src[e];
}

// ---------------------------------------------------------------------------
// Swapped-operand MFMA: D = W · x^T. Lane owns ONE output row; reg 0..3 of
// each acc are 4 consecutive h columns -> float4 contiguous scatter stores.
// Software pipeline: per k-step, issue W-frag loads (L2) first, then NEXT
// k-step's x loads (HBM) -> MFMA's waitcnt on W leaves the x prefetch in
// flight (vmcnt FIFO). 1-deep x prefetch keeps VGPR <= 170 (3 waves/SIMD).
// ---------------------------------------------------------------------------
template <int K>
__device__ __forceinline__ void run_type(
    const float* __restrict__ x, const __bf16* __restrict__ Wfrag,
    const float* __restrict__ bias, const int* __restrict__ idx,
    float* __restrict__ out, int M, int blk)
{
    constexpr int KSTEPS = K / 32;
    const int lane = threadIdx.x & 63;
    const int wave = threadIdx.x >> 6;
    const int l15 = lane & 15;
    const int kg = lane >> 4;
    const int rowbase = blk * 128 + wave * 32;

    const int gr0 = rowbase + l15;
    const int gr1 = gr0 + 16;
    const int r0c = gr0 < M ? gr0 : M - 1;
    const int r1c = gr1 < M ? gr1 : M - 1;

    const float* a0p = x + (size_t)r0c * K + kg * 8;
    const float* a1p = x + (size_t)r1c * K + kg * 8;

    // ks=0 x loads issue first (longest latency path)
    f32x4 c0a = *reinterpret_cast<const f32x4*>(a0p);
    f32x4 c0b = *reinterpret_cast<const f32x4*>(a0p + 4);
    f32x4 c1a = *reinterpret_cast<const f32x4*>(a1p);
    f32x4 c1b = *reinterpret_cast<const f32x4*>(a1p + 4);

    const int orow0 = idx[r0c];
    const int orow1 = idx[r1c];

    const bf16x8* wbase = reinterpret_cast<const bf16x8*>(Wfrag) + lane;

    f32x4 acc[2][8] = {};

#pragma unroll
    for (int ks = 0; ks < KSTEPS; ++ks) {
        // (1) W-frags for this step: oldest in vmcnt FIFO -> MFMA waits only these
        bf16x8 w[8];
#pragma unroll
        for (int hf = 0; hf < 8; ++hf) w[hf] = wbase[(ks * 8 + hf) * 64];

        // (2) prefetch next step's x (stays in flight through this step's MFMAs)
        f32x4 n0a, n0b, n1a, n1b;
        if (ks + 1 < KSTEPS) {
            n0a = *reinterpret_cast<const f32x4*>(a0p + (ks + 1) * 32);
            n0b = *reinterpret_cast<const f32x4*>(a0p + (ks + 1) * 32 + 4);
            n1a = *reinterpret_cast<const f32x4*>(a1p + (ks + 1) * 32);
            n1b = *reinterpret_cast<const f32x4*>(a1p + (ks + 1) * 32 + 4);
        }

        // (3) convert current x (already in regs -> no wait)
        bf16x8 xf0, xf1;
        xf0[0] = (__bf16)c0a[0]; xf0[1] = (__bf16)c0a[1]; xf0[2] = (__bf16)c0a[2]; xf0[3] = (__bf16)c0a[3];
        xf0[4] = (__bf16)c0b[0]; xf0[5] = (__bf16)c0b[1]; xf0[6] = (__bf16)c0b[2]; xf0[7] = (__bf16)c0b[3];
        xf1[0] = (__bf16)c1a[0]; xf1[1] = (__bf16)c1a[1]; xf1[2] = (__bf16)c1a[2]; xf1[3] = (__bf16)c1a[3];
        xf1[4] = (__bf16)c1b[0]; xf1[5] = (__bf16)c1b[1]; xf1[6] = (__bf16)c1b[2]; xf1[7] = (__bf16)c1b[3];

        // (4) MFMAs (wait on W only; x prefetch remains outstanding)
#pragma unroll
        for (int hf = 0; hf < 8; ++hf) {
            acc[0][hf] = __builtin_amdgcn_mfma_f32_16x16x32_bf16(w[hf], xf0, acc[0][hf], 0, 0, 0);
            acc[1][hf] = __builtin_amdgcn_mfma_f32_16x16x32_bf16(w[hf], xf1, acc[1][hf], 0, 0, 0);
        }

        if (ks + 1 < KSTEPS) { c0a = n0a; c0b = n0b; c1a = n1a; c1b = n1b; }
    }

    // Epilogue: acc[mf][hf] reg r corresponds to h = hf*16 + kg*4 + r.
#pragma unroll
    for (int hf = 0; hf < 8; ++hf) {
        f32x4 bv = *reinterpret_cast<const f32x4*>(bias + hf * 16 + kg * 4);
        if (gr0 < M) {
            f32x4 v = acc[0][hf] + bv;
            *reinterpret_cast<f32x4*>(out + (size_t)orow0 * 128 + hf * 16 + kg * 4) = v;
        }
        if (gr1 < M) {
            f32x4 v = acc[1][hf] + bv;
            *reinterpret_cast<f32x4*>(out + (size_t)orow1 * 128 + hf * 16 + kg * 4) = v;
        }
    }
}

// Fused: one grid covers all three types. Longest-K type first (better tail).
__global__ __launch_bounds__(256, 3) void fused_linear_kernel(
    const float* __restrict__ x0, const float* __restrict__ x1, const float* __restrict__ x2,
    const __bf16* __restrict__ Bf0, const __bf16* __restrict__ Bf1, const __bf16* __restrict__ Bf2,
    const float* __restrict__ b0, const float* __restrict__ b1, const float* __restrict__ b2,
    const int* __restrict__ idx0, const int* __restrict__ idx1, const int* __restrict__ idx2,
    float* __restrict__ out, int M0, int M1, int M2, int nb2, int nb21)
{
    int b = blockIdx.x;
    if (b < nb2)       run_type<256>(x2, Bf2, b2, idx2, out, M2, b);
    else if (b < nb21) run_type<128>(x1, Bf1, b1, idx1, out, M1, b - nb2);
    else               run_type<64>(x0, Bf0, b0, idx0, out, M0, b - nb21);
}

extern "C" void kernel_launch(void* const* d_in, const int* in_sizes, int n_in,
                              void* d_out, int out_size, void* d_ws, size_t ws_size,
                              hipStream_t stream) {
    const float* x0 = (const float*)d_in[0];
    const float* x1 = (const float*)d_in[1];
    const float* x2 = (const float*)d_in[2];
    const float* W0 = (const float*)d_in[3];
    const float* b0 = (const float*)d_in[4];
    const float* W1 = (const float*)d_in[5];
    const float* b1 = (const float*)d_in[6];
    const float* W2 = (const float*)d_in[7];
    const float* b2 = (const float*)d_in[8];
    const int* idx0 = (const int*)d_in[9];
    const int* idx1 = (const int*)d_in[10];
    const int* idx2 = (const int*)d_in[11];
    float* out = (float*)d_out;

    const int M0 = in_sizes[9];
    const int M1 = in_sizes[10];
    const int M2 = in_sizes[11];

    __bf16* Bf0 = (__bf16*)d_ws;              // K=64:  8192 bf16
    __bf16* Bf1 = Bf0 + 2 * 8 * 64 * 8;       // K=128: 16384 bf16
    __bf16* Bf2 = Bf1 + 4 * 8 * 64 * 8;       // K=256: 32768 bf16

    prep_all_kernel<<<(7168 + 255) / 256, 256, 0, stream>>>(W0, W1, W2, Bf0, Bf1, Bf2);

    const int nb0 = (M0 + 127) / 128;
    const int nb1 = (M1 + 127) / 128;
    const int nb2 = (M2 + 127) / 128;
    fused_linear_kernel<<<nb0 + nb1 + nb2, 256, 0, stream>>>(
        x0, x1, x2, Bf0, Bf1, Bf2, b0, b1, b2, idx0, idx1, idx2,
        out, M0, M1, M2, nb2, nb2 + nb1);
}